// Round 11
// baseline (2626.786 us; speedup 1.0000x reference)
//
#include <hip/hip_runtime.h>
#include <math.h>

#define NB 128
#define NS 256
#define ND 1024
#define NH 16
#define NC 50
#define NA 32
#define NSD 64
#define NL 6
#define NSTEPS 10
#define NM (NB*NC)     // 6400
#define NKV (NS+1)     // 257

typedef unsigned short u16;
typedef short bf16x8 __attribute__((ext_vector_type(8)));
typedef float f32x4 __attribute__((ext_vector_type(4)));
typedef unsigned short us4 __attribute__((ext_vector_type(4)));
typedef unsigned short us8 __attribute__((ext_vector_type(8)));

typedef __attribute__((address_space(1))) const void* gas_p;
typedef __attribute__((address_space(3))) void* las_p;

__device__ __forceinline__ float b2f(u16 h) { return __uint_as_float(((unsigned int)h) << 16); }
__device__ __forceinline__ u16 f2b(float f) {
  unsigned int u = __float_as_uint(f);
  return (u16)((u + 0x7fffu + ((u >> 16) & 1u)) >> 16);
}
__device__ __forceinline__ void gld16(const void* g, void* l) {
  __builtin_amdgcn_global_load_lds((gas_p)g, (las_p)l, 16, 0, 0);
}

__device__ __forceinline__ float wredsum(float v) {
#pragma unroll
  for (int o = 32; o > 0; o >>= 1) v += __shfl_down(v, o, 64);
  return v;
}
__device__ __forceinline__ void bsum2(float& a, float& b, float* red, int t) {
  float ra = wredsum(a), rb = wredsum(b);
  if ((t & 63) == 0) { red[(t >> 6) * 2] = ra; red[(t >> 6) * 2 + 1] = rb; }
  __syncthreads();
  a = red[0] + red[2] + red[4] + red[6];
  b = red[1] + red[3] + red[5] + red[7];
  __syncthreads();
}

// ---------------- film GEMM v3: A LDS-staged, B DIRECT FROM GLOBAL (frag-packed) ----------
// 8 waves, 128x128 tile, wave grid 2Mx4N (wave-tile 64x32). W (2MB) is L2-resident; B
// fragments are loaded per-wave straight from global in MFMA-fragment order, issued BEFORE
// the A-stage so the compiler's auto-vmcnt for B leaves the A prefetch in flight.
// A: XOR-swizzled dbuf (32KB, aliased with C-staging). XCD swizzle. No K-split/pair-reduce.
__global__ __launch_bounds__(512) void film_gemm(const u16* __restrict__ Ag,
                                                 const u16* __restrict__ Wf,
                                                 u16* __restrict__ Ug) {
  __shared__ __align__(16) u16 smemu[16384];   // 32KB: A dbuf 2x8192 u16; aliased Cs
  const int t = threadIdx.x, lane = t & 63, w = t >> 6;
  const int rb_ = blockIdx.x;
  const int bid = (rb_ & 7) * 50 + (rb_ >> 3);   // bijective XCD swizzle (400 % 8 == 0)
  const int tm = bid >> 3, tn = bid & 7;
  const u16* Ab = Ag + (size_t)tm * 128 * ND;
  // A staging: chunks t, t+512; LDS dest linear; global src chunk = (row, q^(row&7))
  const int sr0 = t >> 3, sq0 = (t & 7) ^ (sr0 & 7);
  const int c1 = t + 512;
  const int sr1 = c1 >> 3, sq1 = (c1 & 7) ^ (sr1 & 7);
  const int wm = w >> 2, wn = w & 3;
  const int wr = wm * 64, wc = wn * 32;
  const int fr = lane & 15, f8 = lane >> 4, r7 = fr & 7;
  // B fragment base: frag-tile (nt, kt) at (nt*32+kt)*512 u16, lane holds lane*8..+7
  const u16* WfB = Wf + ((size_t)(tn * 8 + wn * 2) * 32) * 512 + lane * 8;

  f32x4 acc[4][2];
#pragma unroll
  for (int m = 0; m < 4; ++m)
#pragma unroll
    for (int n = 0; n < 2; ++n)
#pragma unroll
      for (int j = 0; j < 4; ++j) acc[m][n][j] = 0.f;

#define STAGE_A(buf, k0)                                                          \
  gld16(Ab + (size_t)sr0 * ND + (k0) + sq0 * 8, smemu + (buf) * 8192 + w * 512);  \
  gld16(Ab + (size_t)sr1 * ND + (k0) + sq1 * 8, smemu + (buf) * 8192 + 4096 + w * 512);

  STAGE_A(0, 0)
  __syncthreads();

  for (int it = 0; it < 16; ++it) {
    const int cur = it & 1;
    // B fragments first (issued before A stage -> B-wait leaves A in flight)
    bf16x8 bAll[2][2];
#pragma unroll
    for (int ks = 0; ks < 2; ++ks)
#pragma unroll
      for (int n = 0; n < 2; ++n)
        bAll[ks][n] = *(const bf16x8*)(WfB + ((size_t)n * 32 + it * 2 + ks) * 512);
    if (it < 15) { STAGE_A(cur ^ 1, (it + 1) * 64) }
    const u16* Asc = smemu + cur * 8192;
#pragma unroll
    for (int ks = 0; ks < 2; ++ks) {
      const int qp = ks * 4 + f8;
      bf16x8 af[4];
#pragma unroll
      for (int m = 0; m < 4; ++m)
        af[m] = *(const bf16x8*)(Asc + (wr + m * 16 + fr) * 64 + (qp ^ r7) * 8);
#pragma unroll
      for (int m = 0; m < 4; ++m)
#pragma unroll
        for (int n = 0; n < 2; ++n)
          acc[m][n] = __builtin_amdgcn_mfma_f32_16x16x32_bf16(af[m], bAll[ks][n],
                                                              acc[m][n], 0, 0, 0);
    }
    __syncthreads();
  }
#undef STAGE_A

  // coalesced C-write via LDS (Cs aliases the A dbuf; final barrier above protects reads)
  u16* Cs = smemu;
#pragma unroll
  for (int m = 0; m < 4; ++m)
#pragma unroll
    for (int n = 0; n < 2; ++n)
#pragma unroll
      for (int j = 0; j < 4; ++j)
        Cs[(wr + m * 16 + f8 * 4 + j) * 128 + wc + n * 16 + fr] = f2b(acc[m][n][j]);
  __syncthreads();
  {
    const int row = t >> 2, cb0 = (t & 3) * 32;
    u16* dst = Ug + (size_t)(tm * 128 + row) * ND + tn * 128 + cb0;
    const u16* srcl = Cs + row * 128 + cb0;
#pragma unroll
    for (int i = 0; i < 4; ++i) *(us8*)(dst + i * 8) = *(const us8*)(srcl + i * 8);
  }
}

// ------------- packF: filmW[l][k][n] -> MFMA B-fragment order bf16 ------------------------
// dst index for (n,k): ((n>>4)*32 + (k>>5))*512 + ((n&15) + 16*((k>>3)&3))*8 + (k&7)
__global__ __launch_bounds__(256) void packF(const float* __restrict__ src,
                                             u16* __restrict__ dst) {
  __shared__ float tl[64 * 65];
  const int l = blockIdx.z, kt64 = blockIdx.y, nt64 = blockIdx.x;
  const int t = threadIdx.x;
  const float* s = src + (size_t)l * ND * ND + (size_t)(kt64 * 64) * ND + nt64 * 64;
#pragma unroll
  for (int j = 0; j < 4; ++j) {
    const int f = (t + j * 256) * 4;
    const int r = f >> 6, c = f & 63;
    const f32x4 v = *(const f32x4*)&s[(size_t)r * ND + c];
#pragma unroll
    for (int i = 0; i < 4; ++i) tl[r * 65 + c + i] = v[i];
  }
  __syncthreads();
  const int nn = t >> 2, kg = (t & 3) * 16;   // n-local, k-local base (16-aligned)
  us8 o0, o1;
#pragma unroll
  for (int i = 0; i < 8; ++i) o0[i] = f2b(tl[(kg + i) * 65 + nn]);
#pragma unroll
  for (int i = 0; i < 8; ++i) o1[i] = f2b(tl[(kg + 8 + i) * 65 + nn]);
  const int n = nt64 * 64 + nn;
  const int kbase = kt64 * 64 + kg;            // kg in {0,16,32,48}: 16-run stays in k32 tile
  u16* base_ = dst + (size_t)l * ND * ND + ((size_t)(n >> 4) * 32 + (kbase >> 5)) * 512;
  const int lane0 = (n & 15) + 16 * ((kbase >> 3) & 3);
  const int lane1 = (n & 15) + 16 * (((kbase + 8) >> 3) & 3);
  *(us8*)(base_ + lane0 * 8) = o0;
  *(us8*)(base_ + lane1 * 8) = o1;
}

// ---------------- generic MFMA GEMM: C[z][128][N] = A[z][128,1024] @ Bp[z][N][1024]^T -----
__global__ __launch_bounds__(256) void bgemm(const u16* __restrict__ A, const int a_rstride,
    const int a_zoff, const u16* __restrict__ Bp, const long long b_zoff,
    const float* __restrict__ bias, const int bias_zoff, u16* __restrict__ C,
    const int c_rstride, const long long c_zoff) {
  __shared__ u16 As[4096];   // [128][32]
  __shared__ u16 Bs[2048];   // [64][32]
  const int t = threadIdx.x, wv = t >> 6, lane = t & 63;
  const int nt = blockIdx.x, z = blockIdx.y;
  const u16* Ab = A + (size_t)z * a_zoff;
  const u16* Bb = Bp + (size_t)z * b_zoff + (size_t)nt * 64 * ND;
  const int ca = wv * 128 + lane;
  const int ra0 = ca >> 2, qa0 = (ca & 3) * 8;
  const int ca1 = ca + 64;
  const int ra1 = ca1 >> 2, qa1 = (ca1 & 3) * 8;
  const int cbk = wv * 64 + lane;
  const int rb0 = cbk >> 2, qb0 = (cbk & 3) * 8;
  const int wr = (wv >> 1) * 64, wc = (wv & 1) * 32;
  const int fr = lane & 15, fq = (lane >> 4) * 8;

  f32x4 acc[4][2];
#pragma unroll
  for (int m = 0; m < 4; ++m)
#pragma unroll
    for (int n = 0; n < 2; ++n)
#pragma unroll
      for (int j = 0; j < 4; ++j) acc[m][n][j] = 0.f;

  for (int k0 = 0; k0 < ND; k0 += 32) {
    __syncthreads();
    gld16(Ab + (size_t)ra0 * a_rstride + k0 + qa0, As + wv * 1024);
    gld16(Ab + (size_t)ra1 * a_rstride + k0 + qa1, As + wv * 1024 + 512);
    gld16(Bb + (size_t)rb0 * ND + k0 + qb0, Bs + wv * 512);
    __syncthreads();
    bf16x8 af[4], bfv[2];
#pragma unroll
    for (int m = 0; m < 4; ++m) af[m] = *(const bf16x8*)(As + (wr + m * 16 + fr) * 32 + fq);
#pragma unroll
    for (int n = 0; n < 2; ++n) bfv[n] = *(const bf16x8*)(Bs + (wc + n * 16 + fr) * 32 + fq);
#pragma unroll
    for (int m = 0; m < 4; ++m)
#pragma unroll
      for (int n = 0; n < 2; ++n)
        acc[m][n] = __builtin_amdgcn_mfma_f32_16x16x32_bf16(af[m], bfv[n], acc[m][n], 0, 0, 0);
  }
  const int rb = wr + (lane >> 4) * 4;
#pragma unroll
  for (int n = 0; n < 2; ++n) {
    const int col = nt * 64 + wc + n * 16 + fr;
    const float bz = bias[(size_t)z * bias_zoff + col];
#pragma unroll
    for (int m = 0; m < 4; ++m)
#pragma unroll
      for (int j = 0; j < 4; ++j)
        C[(size_t)z * c_zoff + (size_t)(rb + m * 16 + j) * c_rstride + col] =
            f2b(acc[m][n][j] + bz);
  }
}

// ------------- LN + FiLM + exact GELU, wave per row (gamma/beta bf16) ---------------------
__global__ __launch_bounds__(256) void ln_film(const u16* __restrict__ U,
    const float* __restrict__ lb, const float* __restrict__ lg, const float* __restrict__ lbe,
    const u16* __restrict__ gbB, u16* __restrict__ Hout) {
  const int t = threadIdx.x, wv = t >> 6, lane = t & 63;
  const int row = blockIdx.x * 4 + wv;
  const int b = row / NC;
  const int d0 = lane * 16;
  const u16* up = U + (size_t)row * ND + d0;
  us8 u0 = *(const us8*)up;
  us8 u1 = *(const us8*)(up + 8);
  float lbv[16], lgv[16], lbev[16];
#pragma unroll
  for (int i = 0; i < 4; ++i) {
    *(f32x4*)&lbv[i * 4]  = *(const f32x4*)&lb[d0 + i * 4];
    *(f32x4*)&lgv[i * 4]  = *(const f32x4*)&lg[d0 + i * 4];
    *(f32x4*)&lbev[i * 4] = *(const f32x4*)&lbe[d0 + i * 4];
  }
  float x[16];
#pragma unroll
  for (int i = 0; i < 8; ++i) x[i] = b2f((u16)u0[i]) + lbv[i];
#pragma unroll
  for (int i = 0; i < 8; ++i) x[8 + i] = b2f((u16)u1[i]) + lbv[8 + i];
  float s = 0.f, q = 0.f;
#pragma unroll
  for (int i = 0; i < 16; ++i) { s += x[i]; q += x[i] * x[i]; }
#pragma unroll
  for (int o = 32; o > 0; o >>= 1) { s += __shfl_xor(s, o, 64); q += __shfl_xor(q, o, 64); }
  const float m = s * (1.f / ND);
  const float rstd = rsqrtf(q * (1.f / ND) - m * m + 1e-5f);
  const u16* gbb = gbB + (size_t)b * (2 * ND);
  us8 g0 = *(const us8*)(gbb + d0);
  us8 g1 = *(const us8*)(gbb + d0 + 8);
  us8 e0 = *(const us8*)(gbb + ND + d0);
  us8 e1 = *(const us8*)(gbb + ND + d0 + 8);
  us8 o0, o1;
#pragma unroll
  for (int i = 0; i < 16; ++i) {
    const float hh = (x[i] - m) * rstd * lgv[i] + lbev[i];
    const float ga = (i < 8) ? b2f((u16)g0[i]) : b2f((u16)g1[i - 8]);
    const float be = (i < 8) ? b2f((u16)e0[i]) : b2f((u16)e1[i - 8]);
    const float y = (1.f + ga) * hh + be;
    const float gl = 0.5f * y * (1.f + erff(y * 0.70710678118654752f));
    const u16 r = f2b(gl);
    if (i < 8) o0[i] = r; else o1[i - 8] = r;
  }
  u16* op = Hout + (size_t)row * ND + d0;
  *(us8*)op = o0;
  *(us8*)(op + 8) = o1;
}

// ------------- h0 = x@W_ap + (b_ap+temb) + pos -> bf16; coalesced C via LDS ---------------
__global__ __launch_bounds__(256) void h0_mfma(const float* __restrict__ X,
    const u16* __restrict__ WapP, const float* __restrict__ bt,
    const float* __restrict__ pos, u16* __restrict__ Hout) {
  __shared__ u16 As[4096];
  __shared__ u16 Bs[4096];
  __shared__ u16 Cs[16384];    // 128x128 bf16 = 32KB
  const int t = threadIdx.x, wv = t >> 6, lane = t & 63;
  const int r0 = blockIdx.x * 128, c0 = blockIdx.y * 128;
  {
    const int r = t >> 1, hh = (t & 1) * 16;
    const float* xp = X + (size_t)(r0 + r) * NA + hh;
    u16* ad = As + r * 32 + hh;
#pragma unroll
    for (int i = 0; i < 4; ++i) {
      const f32x4 v = *(const f32x4*)(xp + i * 4);
      us4 o;
#pragma unroll
      for (int j = 0; j < 4; ++j) o[j] = f2b(v[j]);
      *(us4*)(ad + i * 4) = o;
    }
  }
  const u16* Bb = WapP + (size_t)c0 * NA;
  {
    const int c = wv * 128 + lane;
    gld16(Bb + (size_t)(c >> 2) * NA + (c & 3) * 8, Bs + wv * 1024);
    const int c1 = c + 64;
    gld16(Bb + (size_t)(c1 >> 2) * NA + (c1 & 3) * 8, Bs + wv * 1024 + 512);
  }
  __syncthreads();
  const int wr = (wv >> 1) * 64, wc = (wv & 1) * 64;
  const int fr = lane & 15, fq = (lane >> 4) * 8;
  bf16x8 af[4], bfv[4];
#pragma unroll
  for (int m = 0; m < 4; ++m) af[m] = *(const bf16x8*)(As + (wr + m * 16 + fr) * 32 + fq);
#pragma unroll
  for (int n = 0; n < 4; ++n) bfv[n] = *(const bf16x8*)(Bs + (wc + n * 16 + fr) * 32 + fq);
  f32x4 acc[4][4];
#pragma unroll
  for (int m = 0; m < 4; ++m)
#pragma unroll
    for (int n = 0; n < 4; ++n) {
#pragma unroll
      for (int j = 0; j < 4; ++j) acc[m][n][j] = 0.f;
      acc[m][n] = __builtin_amdgcn_mfma_f32_16x16x32_bf16(af[m], bfv[n], acc[m][n], 0, 0, 0);
    }
#pragma unroll
  for (int n = 0; n < 4; ++n) {
    const int col = c0 + wc + n * 16 + fr;
    const float btv = bt[col];
#pragma unroll
    for (int m = 0; m < 4; ++m)
#pragma unroll
      for (int j = 0; j < 4; ++j) {
        const int lr = wr + m * 16 + (lane >> 4) * 4 + j;
        const int c = (r0 + lr) % NC;
        Cs[lr * 128 + wc + n * 16 + fr] = f2b(acc[m][n][j] + btv + pos[(size_t)c * ND + col]);
      }
  }
  __syncthreads();
  {
    const int row = t >> 1, cb0 = (t & 1) * 64;
    u16* dst = Hout + (size_t)(r0 + row) * ND + c0 + cb0;
    const u16* srcl = Cs + row * 128 + cb0;
#pragma unroll
    for (int i = 0; i < 8; ++i) *(us8*)(dst + i * 8) = *(const us8*)(srcl + i * 8);
  }
}

// ------------- v = h@W_ad + b_ad ; x_out = x_in + 0.1*v  (MFMA K-reduction) ---------------
__global__ __launch_bounds__(256) void vx_kernel(const u16* __restrict__ Hf,
    const u16* __restrict__ WadP, const float* __restrict__ b_ad,
    const float* __restrict__ Xin, float* __restrict__ Xout) {
  const int t = threadIdx.x, wv = t >> 6, lane = t & 63;
  const int r0 = blockIdx.x * 64 + wv * 16;
  f32x4 a0, a1;
#pragma unroll
  for (int j = 0; j < 4; ++j) { a0[j] = 0.f; a1[j] = 0.f; }
  const u16* ap = Hf + (size_t)(r0 + (lane & 15)) * ND + (lane >> 4) * 8;
  const u16* bp = WadP + lane * 8;
#pragma unroll 4
  for (int kt = 0; kt < 32; ++kt) {
    bf16x8 av = *(const bf16x8*)(ap + kt * 32);
    bf16x8 w0 = *(const bf16x8*)(bp + (kt * 2 + 0) * 512);
    bf16x8 w1 = *(const bf16x8*)(bp + (kt * 2 + 1) * 512);
    a0 = __builtin_amdgcn_mfma_f32_16x16x32_bf16(av, w0, a0, 0, 0, 0);
    a1 = __builtin_amdgcn_mfma_f32_16x16x32_bf16(av, w1, a1, 0, 0, 0);
  }
  const int rr = r0 + (lane >> 4) * 4;
  const int c0 = lane & 15;
#pragma unroll
  for (int j = 0; j < 4; ++j) {
    const int row = rr + j;
    const int i0 = row * NA + c0;
    Xout[i0] = Xin[i0] + 0.1f * (a0[j] + b_ad[c0]);
    const int i1 = row * NA + 16 + c0;
    Xout[i1] = Xin[i1] + 0.1f * (a1[j] + b_ad[16 + c0]);
  }
}

// ------------- generic transpose-pack: dst[z][n][k] = f2b(src[z][k][n]), K=1024 ----------
__global__ __launch_bounds__(256) void packT(const float* __restrict__ src,
    const long long src_zoff, const int srcw, u16* __restrict__ dst,
    const long long dst_zoff) {
  __shared__ float tl[64 * 65];
  const int l = blockIdx.z, kt = blockIdx.y, nt = blockIdx.x;
  const int t = threadIdx.x;
  const float* s = src + (size_t)l * src_zoff + (size_t)(kt * 64) * srcw + nt * 64;
#pragma unroll
  for (int j = 0; j < 4; ++j) {
    const int f = (t + j * 256) * 4;
    const int r = f >> 6, c = f & 63;
    const f32x4 v = *(const f32x4*)&s[(size_t)r * srcw + c];
#pragma unroll
    for (int i = 0; i < 4; ++i) tl[r * 65 + c + i] = v[i];
  }
  __syncthreads();
  const int nn = t >> 2, kg = (t & 3) * 16;
  us8 o0, o1;
#pragma unroll
  for (int i = 0; i < 8; ++i) o0[i] = f2b(tl[(kg + i) * 65 + nn]);
#pragma unroll
  for (int i = 0; i < 8; ++i) o1[i] = f2b(tl[(kg + 8 + i) * 65 + nn]);
  u16* d = dst + (size_t)l * dst_zoff + (size_t)(nt * 64 + nn) * ND + kt * 64 + kg;
  *(us8*)d = o0;
  *(us8*)(d + 8) = o1;
}

// ------------- misc packs: W_ap^T bf16, W_ad frag-pack, bt = b_ap + temb ------------------
__global__ __launch_bounds__(256) void prep_misc(const float* __restrict__ W_ap,
    const float* __restrict__ W_ad, u16* __restrict__ WapP, u16* __restrict__ WadP,
    const float* __restrict__ b_ap, float* __restrict__ bt) {
  const int id = blockIdx.x * 256 + threadIdx.x;  // 0..8191
#pragma unroll
  for (int i = 0; i < 4; ++i) {
    const int e = id * 4 + i;
    const int n = e >> 5, k = e & 31;
    WapP[e] = f2b(W_ap[k * ND + n]);
  }
#pragma unroll
  for (int i = 0; i < 4; ++i) {
    const int e = id * 4 + i;
    const int kt = e >> 10, rem = e & 1023;
    const int at = rem >> 9, rem2 = rem & 511;
    const int ln = rem2 >> 3, j = rem2 & 7;
    const int k = kt * 32 + (ln >> 4) * 8 + j;
    const int col = at * 16 + (ln & 15);
    WadP[e] = f2b(W_ad[k * NA + col]);
  }
  if (id < 2560) {
#pragma unroll
    for (int i = 0; i < 4; ++i) {
      const int e = id * 4 + i;
      const int s = e >> 10, d = e & 1023;
      const double lam = 6.907755278982137 / 511.0;  // log(1000)/511
      const double tt = 0.1 * (double)s;
      double v;
      if (d < 512) v = sin(tt * exp(lam * (double)d));
      else         v = cos(tt * exp(lam * (double)(d - 512)));
      bt[e] = (float)v + b_ap[d];
    }
  }
}

// ------------- se_d = LN(state@W_se + b_se) ----------------------------------------------
__global__ __launch_bounds__(256) void se_kernel(const float* __restrict__ state,
    const float* __restrict__ W_se, const float* __restrict__ b_se,
    const float* __restrict__ g_se, const float* __restrict__ be_se,
    float* __restrict__ se_d) {
  __shared__ float xs[NSD];
  __shared__ float red[8];
  const int b = blockIdx.x, t = threadIdx.x;
  if (t < NSD) xs[t] = state[b * NSD + t];
  __syncthreads();
  const int d0 = t * 4;
  float acc[4];
#pragma unroll
  for (int i = 0; i < 4; ++i) acc[i] = b_se[d0 + i];
  for (int k = 0; k < NSD; ++k) {
    const float xv = xs[k];
    const f32x4 wv = *(const f32x4*)&W_se[(size_t)k * ND + d0];
#pragma unroll
    for (int i = 0; i < 4; ++i) acc[i] += xv * wv[i];
  }
  float s = acc[0] + acc[1] + acc[2] + acc[3];
  float q = acc[0]*acc[0] + acc[1]*acc[1] + acc[2]*acc[2] + acc[3]*acc[3];
  bsum2(s, q, red, t);
  const float m = s * (1.f / ND);
  const float rstd = rsqrtf(q * (1.f / ND) - m * m + 1e-5f);
#pragma unroll
  for (int i = 0; i < 4; ++i)
    se_d[(size_t)b * ND + d0 + i] = (acc[i] - m) * rstd * g_se[d0 + i] + be_se[d0 + i];
}

// ------------- qn = LN(mem_latent) --------------------------------------------------------
__global__ __launch_bounds__(256) void q1_kernel(const float* __restrict__ lat,
    const float* __restrict__ g_q, const float* __restrict__ be_q, float* __restrict__ qn) {
  __shared__ float red[8];
  const int t = threadIdx.x;
  const int d0 = t * 4;
  const f32x4 x = *(const f32x4*)&lat[d0];
  float s = x[0] + x[1] + x[2] + x[3];
  float q = x[0]*x[0] + x[1]*x[1] + x[2]*x[2] + x[3]*x[3];
  bsum2(s, q, red, t);
  const float m = s * (1.f / ND);
  const float rstd = rsqrtf(q * (1.f / ND) - m * m + 1e-5f);
#pragma unroll
  for (int i = 0; i < 4; ++i)
    qn[d0 + i] = (x[i] - m) * rstd * g_q[d0 + i] + be_q[d0 + i];
}

// ------------- qh: split-k GEMV ------------------------------------------------------------
__global__ __launch_bounds__(256) void q2_split(const float* __restrict__ qn,
    const float* __restrict__ Wq, float* __restrict__ part) {
  __shared__ float ql[64];
  const int cc = blockIdx.x, kc = blockIdx.y, t = threadIdx.x;
  if (t < 64) ql[t] = qn[kc * 64 + t];
  __syncthreads();
  const int c = cc * 256 + t;
  float acc = 0.f;
#pragma unroll 8
  for (int k = 0; k < 64; ++k) acc += ql[k] * Wq[(size_t)(kc * 64 + k) * ND + c];
  part[kc * ND + c] = acc;
}
__global__ __launch_bounds__(256) void q2_red(const float* __restrict__ part,
    const float* __restrict__ bq, float* __restrict__ qh) {
  const int c = blockIdx.x * 256 + threadIdx.x;
  float a = bq[c];
#pragma unroll
  for (int i = 0; i < 16; ++i) a += part[i * ND + c];
  qh[c] = a;
}

// ------------- probe vectors (coalesced LDS-staged) ---------------------------------------
__global__ __launch_bounds__(256) void q3_kernel(const float* __restrict__ Wk,
    const float* __restrict__ bk, const float* __restrict__ qh,
    float* __restrict__ wTf, float* __restrict__ sb) {
  __shared__ float ql[ND];
  __shared__ float wl[4 * ND];
  const int t = threadIdx.x;
  *(f32x4*)&ql[t * 4] = *(const f32x4*)&qh[t * 4];
  const int d0 = blockIdx.x * 4;
  const float* src = Wk + (size_t)d0 * ND;
#pragma unroll
  for (int i = 0; i < 4; ++i)
    *(f32x4*)&wl[(i * 256 + t) * 4] = *(const f32x4*)&src[(size_t)(i * 256 + t) * 4];
  __syncthreads();
  if (t < 64) {
    const int dl = t >> 4, h = t & 15;
    const float* wr_ = wl + dl * ND + h * 64;
    const float* qr = ql + h * 64;
    float acc = 0.f;
#pragma unroll 8
    for (int j = 0; j < 64; ++j) acc += wr_[j] * qr[j];
    wTf[h * ND + d0 + dl] = acc * 0.125f;
  } else if (blockIdx.x == 0 && t >= 64 && t < 80) {
    const int h = t - 64;
    float sv = 0.f;
    for (int j = 0; j < 64; ++j) sv += bk[h * 64 + j] * ql[h * 64 + j];
    sb[h] = sv * 0.125f;
  }
}

// ------------- fold LN into probes; gwP = MFMA-B-fragment-packed bf16 gw -------------------
__global__ __launch_bounds__(256) void q4_kernel(const float* __restrict__ wTf,
    const float* __restrict__ g_kv, const float* __restrict__ be_kv,
    const float* __restrict__ sb, u16* __restrict__ gwP, float* __restrict__ cgw,
    float* __restrict__ cbw) {
  __shared__ float red[8];
  const int h = blockIdx.x, t = threadIdx.x;
  float pg = 0.f, pb = 0.f;
  for (int d = t; d < ND; d += 256) {
    const float w = wTf[h * ND + d];
    const float gw = g_kv[d] * w;
    gwP[(d >> 5) * 512 + (h + 16 * ((d >> 3) & 3)) * 8 + (d & 7)] = f2b(gw);
    pg += gw;
    pb += be_kv[d] * w;
  }
  bsum2(pg, pb, red, t);
  if (t == 0) { cgw[h] = pg; cbw[h] = pb + sb[h]; }
}

// ------------- scores: MFMA tall-skinny, 16 rows/wave x 16 heads, K=1024 ------------------
__global__ __launch_bounds__(256) void scores3(const float* __restrict__ reasoning,
    const float* __restrict__ se_d, const u16* __restrict__ gwP,
    const float* __restrict__ cgw, const float* __restrict__ cbw,
    float* __restrict__ scores, float* __restrict__ stats) {
  __shared__ u16 gwl[16384];     // 32 KB: B-fragments for all 32 k-tiles
  __shared__ float smv[4][16], srv[4][16];
  const int t = threadIdx.x, wv = t >> 6, lane = t & 63;
#pragma unroll
  for (int i = 0; i < 8; ++i)
    gld16(gwP + (i * 256 + t) * 8, gwl + i * 2048 + wv * 512);
  const int r0 = blockIdx.x * 64 + wv * 16;
  const int rowA = r0 + (lane & 15);
  const unsigned bA = (unsigned)rowA / NKV;
  const int kA = rowA - bA * NKV;
  const float* ptr = ((kA < NS) ? reasoning + ((size_t)bA * NS + kA) * ND
                                : se_d + (size_t)bA * ND) + (lane >> 4) * 8;
  __syncthreads();
  f32x4 acc;
#pragma unroll
  for (int j = 0; j < 4; ++j) acc[j] = 0.f;
  float s = 0.f, q = 0.f;
  for (int kt = 0; kt < 32; ++kt) {
    const f32x4 v0 = *(const f32x4*)(ptr + kt * 32);
    const f32x4 v1 = *(const f32x4*)(ptr + kt * 32 + 4);
    bf16x8 af;
#pragma unroll
    for (int j = 0; j < 4; ++j) {
      af[j] = (short)f2b(v0[j]);
      af[4 + j] = (short)f2b(v1[j]);
      s += v0[j] + v1[j];
      q += v0[j] * v0[j] + v1[j] * v1[j];
    }
    const bf16x8 bfr = *(const bf16x8*)(gwl + kt * 512 + lane * 8);
    acc = __builtin_amdgcn_mfma_f32_16x16x32_bf16(af, bfr, acc, 0, 0, 0);
  }
  s += __shfl_xor(s, 16, 64); s += __shfl_xor(s, 32, 64);
  q += __shfl_xor(q, 16, 64); q += __shfl_xor(q, 32, 64);
  const float m = s * (1.f / ND);
  const float rstd = rsqrtf(q * (1.f / ND) - m * m + 1e-5f);
  if (lane < 16) {
    smv[wv][lane] = m; srv[wv][lane] = rstd;
    const int row = r0 + lane;
    stats[(size_t)row * 2] = m;
    stats[(size_t)row * 2 + 1] = rstd;
  }
  __syncthreads();
  const int h = lane & 15;
  const float cg = cgw[h], cb = cbw[h];
#pragma unroll
  for (int j = 0; j < 4; ++j) {
    const int lr = (lane >> 4) * 4 + j;
    const int row = r0 + lr;
    const float mm = smv[wv][lr], rr = srv[wv][lr];
    const unsigned b = (unsigned)row / NKV;
    const int k = row - b * NKV;
    scores[((size_t)b * NH + h) * NKV + k] = rr * acc[j] - rr * mm * cg + cb;
  }
}

// ------------- softmax + streaming weighted sum -> ctxb bf16 ------------------------------
__global__ __launch_bounds__(256) void ctx2(const float* __restrict__ reasoning,
    const float* __restrict__ se_d, const float* __restrict__ scores,
    const float* __restrict__ stats, const float* __restrict__ g_kv,
    const float* __restrict__ be_kv, u16* __restrict__ ctxb) {
  __shared__ float sc[NH][260];
  __shared__ float stm[NKV], str[NKV];
  __shared__ float c1s[NH];
  const int chunk = blockIdx.x, b = blockIdx.y;
  const int t = threadIdx.x, wv = t >> 6, lane = t & 63;
#pragma unroll
  for (int h = 0; h < NH; ++h)
    for (int k = t; k < NKV; k += 256) sc[h][k] = scores[((size_t)b * NH + h) * NKV + k];
  for (int k = t; k < NKV; k += 256) {
    stm[k] = stats[((size_t)b * NKV + k) * 2];
    str[k] = stats[((size_t)b * NKV + k) * 2 + 1];
  }
  __syncthreads();
#pragma unroll
  for (int hh = 0; hh < 4; ++hh) {
    const int h = wv * 4 + hh;
    float mx = -1e30f;
    for (int i = 0; i < 5; ++i) { const int k = lane + i * 64; if (k < NKV) mx = fmaxf(mx, sc[h][k]); }
#pragma unroll
    for (int o = 32; o > 0; o >>= 1) mx = fmaxf(mx, __shfl_xor(mx, o, 64));
    float sm = 0.f;
    for (int i = 0; i < 5; ++i) {
      const int k = lane + i * 64;
      if (k < NKV) { const float e = __expf(sc[h][k] - mx); sc[h][k] = e; sm += e; }
    }
#pragma unroll
    for (int o = 32; o > 0; o >>= 1) sm += __shfl_xor(sm, o, 64);
    const float inv = 1.f / sm;
    float c1 = 0.f;
    for (int i = 0; i < 5; ++i) {
      const int k = lane + i * 64;
      if (k < NKV) {
        const float a = sc[h][k] * inv * str[k];
        sc[h][k] = a;
        c1 += a * stm[k];
      }
    }
#pragma unroll
    for (int o = 32; o > 0; o >>= 1) c1 += __shfl_xor(c1, o, 64);
    if (lane == 0) c1s[h] = c1;
  }
  __syncthreads();
  const int c = chunk * 256 + t;
  const float g = g_kv[c], be = be_kv[c];
  float acc[16];
#pragma unroll
  for (int h = 0; h < 16; ++h) acc[h] = 0.f;
  const float* xc = reasoning + (size_t)b * NS * ND + c;
#pragma unroll 2
  for (int k4 = 0; k4 < 64; ++k4) {
    const float x0 = xc[(size_t)(k4 * 4 + 0) * ND];
    const float x1 = xc[(size_t)(k4 * 4 + 1) * ND];
    const float x2 = xc[(size_t)(k4 * 4 + 2) * ND];
    const float x3 = xc[(size_t)(k4 * 4 + 3) * ND];
#pragma unroll
    for (int h = 0; h < 16; ++h) {
      const f32x4 w = *(const f32x4*)&sc[h][k4 * 4];
      acc[h] += w[0] * x0 + w[1] * x1 + w[2] * x2 + w[3] * x3;
    }
  }
  {
    const float xs = se_d[(size_t)b * ND + c];
#pragma unroll
    for (int h = 0; h < 16; ++h) acc[h] += sc[h][NS] * xs;
  }
#pragma unroll
  for (int h = 0; h < 16; ++h)
    ctxb[((size_t)b * NH + h) * ND + c] = f2b(g * (acc[h] - c1s[h]) + be);
}

extern "C" void kernel_launch(void* const* d_in, const int* in_sizes, int n_in,
                              void* d_out, int out_size, void* d_ws, size_t ws_size,
                              hipStream_t stream) {
  (void)in_sizes; (void)n_in; (void)out_size; (void)ws_size;
  const float* reasoning = (const float*)d_in[0];
  const float* state  = (const float*)d_in[1];
  const float* x0     = (const float*)d_in[2];
  const float* W_se   = (const float*)d_in[3];
  const float* b_se   = (const float*)d_in[4];
  const float* g_se   = (const float*)d_in[5];
  const float* be_se  = (const float*)d_in[6];
  const float* W_ap   = (const float*)d_in[7];
  const float* b_ap   = (const float*)d_in[8];
  const float* W_ad   = (const float*)d_in[9];
  const float* b_ad   = (const float*)d_in[10];
  const float* mem_latent = (const float*)d_in[11];
  const float* Wq = (const float*)d_in[12]; const float* bq = (const float*)d_in[13];
  const float* Wk = (const float*)d_in[14]; const float* bk = (const float*)d_in[15];
  const float* Wv = (const float*)d_in[16]; const float* bv = (const float*)d_in[17];
  const float* Wo = (const float*)d_in[18]; const float* bo = (const float*)d_in[19];
  const float* g_q  = (const float*)d_in[20]; const float* be_q  = (const float*)d_in[21];
  const float* g_kv = (const float*)d_in[22]; const float* be_kv = (const float*)d_in[23];
  const float* W_fp = (const float*)d_in[24]; const float* b_fp = (const float*)d_in[25];
  const float* pos_emb = (const float*)d_in[26];
  const float* filmW  = (const float*)d_in[27]; const float* filmb  = (const float*)d_in[28];
  const float* filmg  = (const float*)d_in[29]; const float* filmbe = (const float*)d_in[30];
  const float* filmWf = (const float*)d_in[31]; const float* filmbf = (const float*)d_in[32];

  char* base = (char*)d_ws;
  size_t off = 0;
  auto alloc = [&](size_t bytes) -> void* {
    void* p = base + off;
    off += (bytes + 255) & ~(size_t)255;
    return p;
  };
  u16*  Wfrag   = (u16*)alloc((size_t)NL * ND * ND * 2);        // filmW frag-packed
  u16*  Wfp2    = (u16*)alloc((size_t)NL * 2 * ND * ND * 2);    // filmWf^T
  u16*  Wvp     = (u16*)alloc((size_t)ND * ND * 2);
  u16*  Wop     = (u16*)alloc((size_t)ND * ND * 2);
  u16*  Wfpp    = (u16*)alloc((size_t)ND * ND * 2);
  u16*  WapP    = (u16*)alloc((size_t)NA * ND * 2);
  u16*  WadP    = (u16*)alloc((size_t)32768 * 2);
  float* bt     = (float*)alloc((size_t)NSTEPS * ND * 4);
  float* se_d   = (float*)alloc((size_t)NB * ND * 4);
  float* qn     = (float*)alloc((size_t)ND * 4);
  float* qh     = (float*)alloc((size_t)ND * 4);
  float* part   = (float*)alloc((size_t)16 * ND * 4);
  float* wTf    = (float*)alloc((size_t)NH * ND * 4);
  float* sb     = (float*)alloc((size_t)NH * 4);
  u16*  gwP     = (u16*)alloc((size_t)NH * ND * 2);
  float* cgw    = (float*)alloc((size_t)NH * 4);
  float* cbw    = (float*)alloc((size_t)NH * 4);
  float* stats  = (float*)alloc((size_t)NB * NKV * 2 * 4);
  float* scores = (float*)alloc((size_t)NB * NH * NKV * 4);
  u16*  ctxb    = (u16*)alloc((size_t)NB * NH * ND * 2);
  u16*  mem_pre = (u16*)alloc((size_t)NB * ND * 2);
  u16*  memb    = (u16*)alloc((size_t)NB * ND * 2);
  u16*  fvb     = (u16*)alloc((size_t)NB * ND * 2);
  u16*  gbB     = (u16*)alloc((size_t)NL * NB * 2 * ND * 2);
  u16*  hbuf    = (u16*)alloc((size_t)NM * ND * 2);
  u16*  ubuf    = (u16*)alloc((size_t)NM * ND * 2);

  // ---- weight packs ----
  packF<<<dim3(16, 16, NL), 256, 0, stream>>>(filmW, Wfrag);
  packT<<<dim3(32, 16, NL), 256, 0, stream>>>(filmWf, (long long)ND * 2 * ND, 2 * ND, Wfp2,
                                              (long long)2 * ND * ND);
  packT<<<dim3(16, 16, 1), 256, 0, stream>>>(Wv, 0, ND, Wvp, 0);
  packT<<<dim3(16, 16, 1), 256, 0, stream>>>(Wo, 0, ND, Wop, 0);
  packT<<<dim3(16, 16, 1), 256, 0, stream>>>(W_fp, 0, ND, Wfpp, 0);
  prep_misc<<<32, 256, 0, stream>>>(W_ap, W_ad, WapP, WadP, b_ap, bt);

  // ---- attention / conditioning chain ----
  se_kernel<<<NB, 256, 0, stream>>>(state, W_se, b_se, g_se, be_se, se_d);
  q1_kernel<<<1, 256, 0, stream>>>(mem_latent, g_q, be_q, qn);
  q2_split<<<dim3(4, 16), 256, 0, stream>>>(qn, Wq, part);
  q2_red<<<4, 256, 0, stream>>>(part, bq, qh);
  q3_kernel<<<256, 256, 0, stream>>>(Wk, bk, qh, wTf, sb);
  q4_kernel<<<NH, 256, 0, stream>>>(wTf, g_kv, be_kv, sb, gwP, cgw, cbw);
  scores3<<<(NB * NKV) / 64, 256, 0, stream>>>(reasoning, se_d, gwP, cgw, cbw, scores, stats);
  ctx2<<<dim3(4, NB), 256, 0, stream>>>(reasoning, se_d, scores, stats, g_kv, be_kv, ctxb);
  bgemm<<<dim3(1, 16), 256, 0, stream>>>(ctxb, NH * ND, ND, Wvp, (long long)64 * ND, bv, 64,
                                         mem_pre, ND, 64);
  bgemm<<<dim3(16, 1), 256, 0, stream>>>(mem_pre, ND, 0, Wop, 0, bo, 0, memb, ND, 0);
  bgemm<<<dim3(16, 1), 256, 0, stream>>>(memb, ND, 0, Wfpp, 0, b_fp, 0, fvb, ND, 0);
  bgemm<<<dim3(32, NL), 256, 0, stream>>>(fvb, ND, 0, Wfp2, (long long)2 * ND * ND, filmbf,
                                          2 * ND, gbB, 2 * ND, (long long)NB * 2 * ND);

  // ---- flow-matching Euler loop ----
  for (int s = 0; s < NSTEPS; ++s) {
    const float* xin = (s == 0) ? x0 : (const float*)d_out;
    h0_mfma<<<dim3(NM / 128, 8), 256, 0, stream>>>(xin, WapP, bt + (size_t)s * ND, pos_emb,
                                                   hbuf);
    for (int l = 0; l < NL; ++l) {
      film_gemm<<<400, 512, 0, stream>>>(hbuf, Wfrag + (size_t)l * ND * ND, ubuf);
      ln_film<<<NM / 4, 256, 0, stream>>>(ubuf, filmb + (size_t)l * ND, filmg + (size_t)l * ND,
                                          filmbe + (size_t)l * ND,
                                          gbB + (size_t)l * NB * 2 * ND, hbuf);
    }
    vx_kernel<<<NM / 64, 256, 0, stream>>>(hbuf, WadP, b_ad, xin, (float*)d_out);
  }
}

// Round 12
// 2490.583 us; speedup vs baseline: 1.0547x; 1.0547x over previous
//
#include <hip/hip_runtime.h>
#include <math.h>

#define NB 128
#define NS 256
#define ND 1024
#define NH 16
#define NC 50
#define NA 32
#define NSD 64
#define NL 6
#define NSTEPS 10
#define NM (NB*NC)     // 6400
#define NKV (NS+1)     // 257

typedef unsigned short u16;
typedef short bf16x8 __attribute__((ext_vector_type(8)));
typedef float f32x4 __attribute__((ext_vector_type(4)));
typedef unsigned short us4 __attribute__((ext_vector_type(4)));
typedef unsigned short us8 __attribute__((ext_vector_type(8)));

typedef __attribute__((address_space(1))) const void* gas_p;
typedef __attribute__((address_space(3))) void* las_p;

__device__ __forceinline__ float b2f(u16 h) { return __uint_as_float(((unsigned int)h) << 16); }
__device__ __forceinline__ u16 f2b(float f) {
  unsigned int u = __float_as_uint(f);
  return (u16)((u + 0x7fffu + ((u >> 16) & 1u)) >> 16);
}
__device__ __forceinline__ void gld16(const void* g, void* l) {
  __builtin_amdgcn_global_load_lds((gas_p)g, (las_p)l, 16, 0, 0);
}

__device__ __forceinline__ float wredsum(float v) {
#pragma unroll
  for (int o = 32; o > 0; o >>= 1) v += __shfl_down(v, o, 64);
  return v;
}
__device__ __forceinline__ void bsum2(float& a, float& b, float* red, int t) {
  float ra = wredsum(a), rb = wredsum(b);
  if ((t & 63) == 0) { red[(t >> 6) * 2] = ra; red[(t >> 6) * 2 + 1] = rb; }
  __syncthreads();
  a = red[0] + red[2] + red[4] + red[6];
  b = red[1] + red[3] + red[5] + red[7];
  __syncthreads();
}

// ---------------- film GEMM: [6400,1024] @ bf16 W^T-packed -> u bf16 ----------------------
// Best-measured config (r10): 8 waves, 128x128 tile, K-split wave pairing, XOR-swizzled
// staging (both-sides), XCD swizzle, f32 pair-reduce + coalesced C via LDS, and a
// 3-deep A / 2-deep B pipeline with raw s_barrier + counted s_waitcnt vmcnt(2).
// Issue order B(it+1) then A(it+2): vmcnt(2) leaves only the newest A-pair outstanding,
// so each wave's loads for iter it+1 are complete BEFORE the barrier -> race-free.
// NOTE (r8): no device-scope fences/atomics in hot loops (cross-XCD L2 visibility = ~8x).
// NOTE (r11): L2-resident B still prefers global_load_lds staging over per-wave direct
// fragment loads (B-direct was -5%).
__global__ __launch_bounds__(512) void film_gemm(const u16* __restrict__ Ag,
                                                 const u16* __restrict__ Bg,
                                                 u16* __restrict__ Ug) {
  __shared__ __align__(16) char smemc[81920];   // 80KB: A 3x16KB @0, B 2x16KB @49152B
  u16* smemu = (u16*)smemc;
  const int t = threadIdx.x, lane = t & 63, w = t >> 6;
  const int rb_ = blockIdx.x;
  const int bid = (rb_ & 7) * 50 + (rb_ >> 3);   // bijective XCD swizzle (400 % 8 == 0)
  const int tm = bid >> 3, tn = bid & 7;
  const u16* Ab = Ag + (size_t)tm * 128 * ND;
  const u16* Bb = Bg + (size_t)tn * 128 * ND;
  // staging: chunks t, t+512; LDS dest linear; global src chunk = (row, q^(row&7))
  const int c0 = t, c1 = t + 512;
  const int sr0 = c0 >> 3, sq0 = (c0 & 7) ^ (sr0 & 7);
  const int sr1 = c1 >> 3, sq1 = (c1 & 7) ^ (sr1 & 7);
  const int wq = w & 3, ksel = w >> 2;
  const int wr = (wq >> 1) * 64, wc = (wq & 1) * 64;
  const int fr = lane & 15, f8 = lane >> 4, r7 = fr & 7;
  const int qp = ksel * 4 + f8;

  f32x4 acc[4][4];
#pragma unroll
  for (int m = 0; m < 4; ++m)
#pragma unroll
    for (int n = 0; n < 4; ++n)
#pragma unroll
      for (int j = 0; j < 4; ++j) acc[m][n][j] = 0.f;

#define STAGE_A(bi, k0)                                                           \
  gld16(Ab + (size_t)sr0 * ND + (k0) + sq0 * 8, smemu + (bi) * 8192 + w * 512);   \
  gld16(Ab + (size_t)sr1 * ND + (k0) + sq1 * 8, smemu + (bi) * 8192 + 4096 + w * 512);
#define STAGE_B(bj, k0)                                                           \
  gld16(Bb + (size_t)sr0 * ND + (k0) + sq0 * 8, smemu + 24576 + (bj) * 8192 + w * 512); \
  gld16(Bb + (size_t)sr1 * ND + (k0) + sq1 * 8, smemu + 24576 + (bj) * 8192 + 4096 + w * 512);
#define COMPUTE_IT(it)                                                            \
  {                                                                               \
    const u16* Asc = smemu + ((it) % 3) * 8192;                                   \
    const u16* Bsc = smemu + 24576 + ((it) & 1) * 8192;                           \
    bf16x8 af[4], bfv[4];                                                         \
    _Pragma("unroll")                                                             \
    for (int m = 0; m < 4; ++m)                                                   \
      af[m] = *(const bf16x8*)(Asc + (wr + m * 16 + fr) * 64 + (qp ^ r7) * 8);    \
    _Pragma("unroll")                                                             \
    for (int n = 0; n < 4; ++n)                                                   \
      bfv[n] = *(const bf16x8*)(Bsc + (wc + n * 16 + fr) * 64 + (qp ^ r7) * 8);   \
    _Pragma("unroll")                                                             \
    for (int m = 0; m < 4; ++m)                                                   \
      _Pragma("unroll")                                                           \
      for (int n = 0; n < 4; ++n)                                                 \
        acc[m][n] = __builtin_amdgcn_mfma_f32_16x16x32_bf16(af[m], bfv[n],        \
                                                            acc[m][n], 0, 0, 0); \
  }
#define PIPE_BARRIER(N)                                                           \
  asm volatile("s_waitcnt vmcnt(" #N ")" ::: "memory");                           \
  __builtin_amdgcn_sched_barrier(0);                                              \
  __builtin_amdgcn_s_barrier();                                                   \
  __builtin_amdgcn_sched_barrier(0);

  // prologue: B(0), A(0) must land; A(1) may stay in flight (newest 2)
  STAGE_B(0, 0)
  STAGE_A(0, 0)
  STAGE_A(1, 64)
  PIPE_BARRIER(2)

  for (int it = 0; it < 14; ++it) {
    STAGE_B((it + 1) & 1, (it + 1) * 64)
    STAGE_A((it + 2) % 3, (it + 2) * 64)
    COMPUTE_IT(it)
    PIPE_BARRIER(2)          // newest 2 = A(it+2) pair; B(it+1), A(it+1) complete
  }
  // it = 14: last B prefetch, drain everything for the tail
  STAGE_B(1, 960)
  COMPUTE_IT(14)
  PIPE_BARRIER(0)
  // it = 15
  COMPUTE_IT(15)
  __syncthreads();
#undef STAGE_A
#undef STAGE_B
#undef COMPUTE_IT
#undef PIPE_BARRIER

  // ---- K-split pair reduce: upper waves dump f32 partials, lower waves add ----
  float* Cred = (float*)smemc;
  if (w >= 4) {
    const int base = (w - 4) * 4096;
#pragma unroll
    for (int m = 0; m < 4; ++m)
#pragma unroll
      for (int n = 0; n < 4; ++n)
#pragma unroll
        for (int j = 0; j < 4; ++j)
          Cred[base + (m * 16 + f8 * 4 + j) * 64 + n * 16 + fr] = acc[m][n][j];
  }
  __syncthreads();
  if (w < 4) {
    const int base = w * 4096;
#pragma unroll
    for (int m = 0; m < 4; ++m)
#pragma unroll
      for (int n = 0; n < 4; ++n)
#pragma unroll
        for (int j = 0; j < 4; ++j)
          acc[m][n][j] += Cred[base + (m * 16 + f8 * 4 + j) * 64 + n * 16 + fr];
  }
  __syncthreads();                               // partial reads done before overwrite
  u16* Cs = smemu;                               // bf16 [128][128] = 32KB
  if (w < 4) {
#pragma unroll
    for (int m = 0; m < 4; ++m)
#pragma unroll
      for (int n = 0; n < 4; ++n)
#pragma unroll
        for (int j = 0; j < 4; ++j)
          Cs[(wr + m * 16 + f8 * 4 + j) * 128 + wc + n * 16 + fr] = f2b(acc[m][n][j]);
  }
  __syncthreads();
  {
    const int row = t >> 2, cb0 = (t & 3) * 32;
    u16* dst = Ug + (size_t)(tm * 128 + row) * ND + tn * 128 + cb0;
    const u16* srcl = Cs + row * 128 + cb0;
#pragma unroll
    for (int i = 0; i < 4; ++i) *(us8*)(dst + i * 8) = *(const us8*)(srcl + i * 8);
  }
}

// ---------------- generic MFMA GEMM: C[z][128][N] = A[z][128,1024] @ Bp[z][N][1024]^T -----
__global__ __launch_bounds__(256) void bgemm(const u16* __restrict__ A, const int a_rstride,
    const int a_zoff, const u16* __restrict__ Bp, const long long b_zoff,
    const float* __restrict__ bias, const int bias_zoff, u16* __restrict__ C,
    const int c_rstride, const long long c_zoff) {
  __shared__ u16 As[4096];   // [128][32]
  __shared__ u16 Bs[2048];   // [64][32]
  const int t = threadIdx.x, wv = t >> 6, lane = t & 63;
  const int nt = blockIdx.x, z = blockIdx.y;
  const u16* Ab = A + (size_t)z * a_zoff;
  const u16* Bb = Bp + (size_t)z * b_zoff + (size_t)nt * 64 * ND;
  const int ca = wv * 128 + lane;
  const int ra0 = ca >> 2, qa0 = (ca & 3) * 8;
  const int ca1 = ca + 64;
  const int ra1 = ca1 >> 2, qa1 = (ca1 & 3) * 8;
  const int cbk = wv * 64 + lane;
  const int rb0 = cbk >> 2, qb0 = (cbk & 3) * 8;
  const int wr = (wv >> 1) * 64, wc = (wv & 1) * 32;
  const int fr = lane & 15, fq = (lane >> 4) * 8;

  f32x4 acc[4][2];
#pragma unroll
  for (int m = 0; m < 4; ++m)
#pragma unroll
    for (int n = 0; n < 2; ++n)
#pragma unroll
      for (int j = 0; j < 4; ++j) acc[m][n][j] = 0.f;

  for (int k0 = 0; k0 < ND; k0 += 32) {
    __syncthreads();
    gld16(Ab + (size_t)ra0 * a_rstride + k0 + qa0, As + wv * 1024);
    gld16(Ab + (size_t)ra1 * a_rstride + k0 + qa1, As + wv * 1024 + 512);
    gld16(Bb + (size_t)rb0 * ND + k0 + qb0, Bs + wv * 512);
    __syncthreads();
    bf16x8 af[4], bfv[2];
#pragma unroll
    for (int m = 0; m < 4; ++m) af[m] = *(const bf16x8*)(As + (wr + m * 16 + fr) * 32 + fq);
#pragma unroll
    for (int n = 0; n < 2; ++n) bfv[n] = *(const bf16x8*)(Bs + (wc + n * 16 + fr) * 32 + fq);
#pragma unroll
    for (int m = 0; m < 4; ++m)
#pragma unroll
      for (int n = 0; n < 2; ++n)
        acc[m][n] = __builtin_amdgcn_mfma_f32_16x16x32_bf16(af[m], bfv[n], acc[m][n], 0, 0, 0);
  }
  const int rb = wr + (lane >> 4) * 4;
#pragma unroll
  for (int n = 0; n < 2; ++n) {
    const int col = nt * 64 + wc + n * 16 + fr;
    const float bz = bias[(size_t)z * bias_zoff + col];
#pragma unroll
    for (int m = 0; m < 4; ++m)
#pragma unroll
      for (int j = 0; j < 4; ++j)
        C[(size_t)z * c_zoff + (size_t)(rb + m * 16 + j) * c_rstride + col] =
            f2b(acc[m][n][j] + bz);
  }
}

// ------------- LN + FiLM + exact GELU, wave per row (gamma/beta bf16) ---------------------
__global__ __launch_bounds__(256) void ln_film(const u16* __restrict__ U,
    const float* __restrict__ lb, const float* __restrict__ lg, const float* __restrict__ lbe,
    const u16* __restrict__ gbB, u16* __restrict__ Hout) {
  const int t = threadIdx.x, wv = t >> 6, lane = t & 63;
  const int row = blockIdx.x * 4 + wv;
  const int b = row / NC;
  const int d0 = lane * 16;
  const u16* up = U + (size_t)row * ND + d0;
  us8 u0 = *(const us8*)up;
  us8 u1 = *(const us8*)(up + 8);
  float lbv[16], lgv[16], lbev[16];
#pragma unroll
  for (int i = 0; i < 4; ++i) {
    *(f32x4*)&lbv[i * 4]  = *(const f32x4*)&lb[d0 + i * 4];
    *(f32x4*)&lgv[i * 4]  = *(const f32x4*)&lg[d0 + i * 4];
    *(f32x4*)&lbev[i * 4] = *(const f32x4*)&lbe[d0 + i * 4];
  }
  float x[16];
#pragma unroll
  for (int i = 0; i < 8; ++i) x[i] = b2f((u16)u0[i]) + lbv[i];
#pragma unroll
  for (int i = 0; i < 8; ++i) x[8 + i] = b2f((u16)u1[i]) + lbv[8 + i];
  float s = 0.f, q = 0.f;
#pragma unroll
  for (int i = 0; i < 16; ++i) { s += x[i]; q += x[i] * x[i]; }
#pragma unroll
  for (int o = 32; o > 0; o >>= 1) { s += __shfl_xor(s, o, 64); q += __shfl_xor(q, o, 64); }
  const float m = s * (1.f / ND);
  const float rstd = rsqrtf(q * (1.f / ND) - m * m + 1e-5f);
  const u16* gbb = gbB + (size_t)b * (2 * ND);
  us8 g0 = *(const us8*)(gbb + d0);
  us8 g1 = *(const us8*)(gbb + d0 + 8);
  us8 e0 = *(const us8*)(gbb + ND + d0);
  us8 e1 = *(const us8*)(gbb + ND + d0 + 8);
  us8 o0, o1;
#pragma unroll
  for (int i = 0; i < 16; ++i) {
    const float hh = (x[i] - m) * rstd * lgv[i] + lbev[i];
    const float ga = (i < 8) ? b2f((u16)g0[i]) : b2f((u16)g1[i - 8]);
    const float be = (i < 8) ? b2f((u16)e0[i]) : b2f((u16)e1[i - 8]);
    const float y = (1.f + ga) * hh + be;
    const float gl = 0.5f * y * (1.f + erff(y * 0.70710678118654752f));
    const u16 r = f2b(gl);
    if (i < 8) o0[i] = r; else o1[i - 8] = r;
  }
  u16* op = Hout + (size_t)row * ND + d0;
  *(us8*)op = o0;
  *(us8*)(op + 8) = o1;
}

// ------------- h0 = x@W_ap + (b_ap+temb) + pos -> bf16; coalesced C via LDS ---------------
__global__ __launch_bounds__(256) void h0_mfma(const float* __restrict__ X,
    const u16* __restrict__ WapP, const float* __restrict__ bt,
    const float* __restrict__ pos, u16* __restrict__ Hout) {
  __shared__ u16 As[4096];
  __shared__ u16 Bs[4096];
  __shared__ u16 Cs[16384];    // 128x128 bf16 = 32KB
  const int t = threadIdx.x, wv = t >> 6, lane = t & 63;
  const int r0 = blockIdx.x * 128, c0 = blockIdx.y * 128;
  {
    const int r = t >> 1, hh = (t & 1) * 16;
    const float* xp = X + (size_t)(r0 + r) * NA + hh;
    u16* ad = As + r * 32 + hh;
#pragma unroll
    for (int i = 0; i < 4; ++i) {
      const f32x4 v = *(const f32x4*)(xp + i * 4);
      us4 o;
#pragma unroll
      for (int j = 0; j < 4; ++j) o[j] = f2b(v[j]);
      *(us4*)(ad + i * 4) = o;
    }
  }
  const u16* Bb = WapP + (size_t)c0 * NA;
  {
    const int c = wv * 128 + lane;
    gld16(Bb + (size_t)(c >> 2) * NA + (c & 3) * 8, Bs + wv * 1024);
    const int c1 = c + 64;
    gld16(Bb + (size_t)(c1 >> 2) * NA + (c1 & 3) * 8, Bs + wv * 1024 + 512);
  }
  __syncthreads();
  const int wr = (wv >> 1) * 64, wc = (wv & 1) * 64;
  const int fr = lane & 15, fq = (lane >> 4) * 8;
  bf16x8 af[4], bfv[4];
#pragma unroll
  for (int m = 0; m < 4; ++m) af[m] = *(const bf16x8*)(As + (wr + m * 16 + fr) * 32 + fq);
#pragma unroll
  for (int n = 0; n < 4; ++n) bfv[n] = *(const bf16x8*)(Bs + (wc + n * 16 + fr) * 32 + fq);
  f32x4 acc[4][4];
#pragma unroll
  for (int m = 0; m < 4; ++m)
#pragma unroll
    for (int n = 0; n < 4; ++n) {
#pragma unroll
      for (int j = 0; j < 4; ++j) acc[m][n][j] = 0.f;
      acc[m][n] = __builtin_amdgcn_mfma_f32_16x16x32_bf16(af[m], bfv[n], acc[m][n], 0, 0, 0);
    }
#pragma unroll
  for (int n = 0; n < 4; ++n) {
    const int col = c0 + wc + n * 16 + fr;
    const float btv = bt[col];
#pragma unroll
    for (int m = 0; m < 4; ++m)
#pragma unroll
      for (int j = 0; j < 4; ++j) {
        const int lr = wr + m * 16 + (lane >> 4) * 4 + j;
        const int c = (r0 + lr) % NC;
        Cs[lr * 128 + wc + n * 16 + fr] = f2b(acc[m][n][j] + btv + pos[(size_t)c * ND + col]);
      }
  }
  __syncthreads();
  {
    const int row = t >> 1, cb0 = (t & 1) * 64;
    u16* dst = Hout + (size_t)(r0 + row) * ND + c0 + cb0;
    const u16* srcl = Cs + row * 128 + cb0;
#pragma unroll
    for (int i = 0; i < 8; ++i) *(us8*)(dst + i * 8) = *(const us8*)(srcl + i * 8);
  }
}

// ------------- v = h@W_ad + b_ad ; x_out = x_in + 0.1*v  (MFMA K-reduction) ---------------
__global__ __launch_bounds__(256) void vx_kernel(const u16* __restrict__ Hf,
    const u16* __restrict__ WadP, const float* __restrict__ b_ad,
    const float* __restrict__ Xin, float* __restrict__ Xout) {
  const int t = threadIdx.x, wv = t >> 6, lane = t & 63;
  const int r0 = blockIdx.x * 64 + wv * 16;
  f32x4 a0, a1;
#pragma unroll
  for (int j = 0; j < 4; ++j) { a0[j] = 0.f; a1[j] = 0.f; }
  const u16* ap = Hf + (size_t)(r0 + (lane & 15)) * ND + (lane >> 4) * 8;
  const u16* bp = WadP + lane * 8;
#pragma unroll 4
  for (int kt = 0; kt < 32; ++kt) {
    bf16x8 av = *(const bf16x8*)(ap + kt * 32);
    bf16x8 w0 = *(const bf16x8*)(bp + (kt * 2 + 0) * 512);
    bf16x8 w1 = *(const bf16x8*)(bp + (kt * 2 + 1) * 512);
    a0 = __builtin_amdgcn_mfma_f32_16x16x32_bf16(av, w0, a0, 0, 0, 0);
    a1 = __builtin_amdgcn_mfma_f32_16x16x32_bf16(av, w1, a1, 0, 0, 0);
  }
  const int rr = r0 + (lane >> 4) * 4;
  const int c0 = lane & 15;
#pragma unroll
  for (int j = 0; j < 4; ++j) {
    const int row = rr + j;
    const int i0 = row * NA + c0;
    Xout[i0] = Xin[i0] + 0.1f * (a0[j] + b_ad[c0]);
    const int i1 = row * NA + 16 + c0;
    Xout[i1] = Xin[i1] + 0.1f * (a1[j] + b_ad[16 + c0]);
  }
}

// ------------- generic transpose-pack: dst[z][n][k] = f2b(src[z][k][n]), K=1024 ----------
__global__ __launch_bounds__(256) void packT(const float* __restrict__ src,
    const long long src_zoff, const int srcw, u16* __restrict__ dst,
    const long long dst_zoff) {
  __shared__ float tl[64 * 65];
  const int l = blockIdx.z, kt = blockIdx.y, nt = blockIdx.x;
  const int t = threadIdx.x;
  const float* s = src + (size_t)l * src_zoff + (size_t)(kt * 64) * srcw + nt * 64;
#pragma unroll
  for (int j = 0; j < 4; ++j) {
    const int f = (t + j * 256) * 4;
    const int r = f >> 6, c = f & 63;
    const f32x4 v = *(const f32x4*)&s[(size_t)r * srcw + c];
#pragma unroll
    for (int i = 0; i < 4; ++i) tl[r * 65 + c + i] = v[i];
  }
  __syncthreads();
  const int nn = t >> 2, kg = (t & 3) * 16;
  us8 o0, o1;
#pragma unroll
  for (int i = 0; i < 8; ++i) o0[i] = f2b(tl[(kg + i) * 65 + nn]);
#pragma unroll
  for (int i = 0; i < 8; ++i) o1[i] = f2b(tl[(kg + 8 + i) * 65 + nn]);
  u16* d = dst + (size_t)l * dst_zoff + (size_t)(nt * 64 + nn) * ND + kt * 64 + kg;
  *(us8*)d = o0;
  *(us8*)(d + 8) = o1;
}

// ------------- misc packs: W_ap^T bf16, W_ad frag-pack, bt = b_ap + temb ------------------
__global__ __launch_bounds__(256) void prep_misc(const float* __restrict__ W_ap,
    const float* __restrict__ W_ad, u16* __restrict__ WapP, u16* __restrict__ WadP,
    const float* __restrict__ b_ap, float* __restrict__ bt) {
  const int id = blockIdx.x * 256 + threadIdx.x;  // 0..8191
#pragma unroll
  for (int i = 0; i < 4; ++i) {
    const int e = id * 4 + i;
    const int n = e >> 5, k = e & 31;
    WapP[e] = f2b(W_ap[k * ND + n]);
  }
#pragma unroll
  for (int i = 0; i < 4; ++i) {
    const int e = id * 4 + i;
    const int kt = e >> 10, rem = e & 1023;
    const int at = rem >> 9, rem2 = rem & 511;
    const int ln = rem2 >> 3, j = rem2 & 7;
    const int k = kt * 32 + (ln >> 4) * 8 + j;
    const int col = at * 16 + (ln & 15);
    WadP[e] = f2b(W_ad[k * NA + col]);
  }
  if (id < 2560) {
#pragma unroll
    for (int i = 0; i < 4; ++i) {
      const int e = id * 4 + i;
      const int s = e >> 10, d = e & 1023;
      const double lam = 6.907755278982137 / 511.0;  // log(1000)/511
      const double tt = 0.1 * (double)s;
      double v;
      if (d < 512) v = sin(tt * exp(lam * (double)d));
      else         v = cos(tt * exp(lam * (double)(d - 512)));
      bt[e] = (float)v + b_ap[d];
    }
  }
}

// ------------- se_d = LN(state@W_se + b_se) ----------------------------------------------
__global__ __launch_bounds__(256) void se_kernel(const float* __restrict__ state,
    const float* __restrict__ W_se, const float* __restrict__ b_se,
    const float* __restrict__ g_se, const float* __restrict__ be_se,
    float* __restrict__ se_d) {
  __shared__ float xs[NSD];
  __shared__ float red[8];
  const int b = blockIdx.x, t = threadIdx.x;
  if (t < NSD) xs[t] = state[b * NSD + t];
  __syncthreads();
  const int d0 = t * 4;
  float acc[4];
#pragma unroll
  for (int i = 0; i < 4; ++i) acc[i] = b_se[d0 + i];
  for (int k = 0; k < NSD; ++k) {
    const float xv = xs[k];
    const f32x4 wv = *(const f32x4*)&W_se[(size_t)k * ND + d0];
#pragma unroll
    for (int i = 0; i < 4; ++i) acc[i] += xv * wv[i];
  }
  float s = acc[0] + acc[1] + acc[2] + acc[3];
  float q = acc[0]*acc[0] + acc[1]*acc[1] + acc[2]*acc[2] + acc[3]*acc[3];
  bsum2(s, q, red, t);
  const float m = s * (1.f / ND);
  const float rstd = rsqrtf(q * (1.f / ND) - m * m + 1e-5f);
#pragma unroll
  for (int i = 0; i < 4; ++i)
    se_d[(size_t)b * ND + d0 + i] = (acc[i] - m) * rstd * g_se[d0 + i] + be_se[d0 + i];
}

// ------------- qn = LN(mem_latent) --------------------------------------------------------
__global__ __launch_bounds__(256) void q1_kernel(const float* __restrict__ lat,
    const float* __restrict__ g_q, const float* __restrict__ be_q, float* __restrict__ qn) {
  __shared__ float red[8];
  const int t = threadIdx.x;
  const int d0 = t * 4;
  const f32x4 x = *(const f32x4*)&lat[d0];
  float s = x[0] + x[1] + x[2] + x[3];
  float q = x[0]*x[0] + x[1]*x[1] + x[2]*x[2] + x[3]*x[3];
  bsum2(s, q, red, t);
  const float m = s * (1.f / ND);
  const float rstd = rsqrtf(q * (1.f / ND) - m * m + 1e-5f);
#pragma unroll
  for (int i = 0; i < 4; ++i)
    qn[d0 + i] = (x[i] - m) * rstd * g_q[d0 + i] + be_q[d0 + i];
}

// ------------- qh: split-k GEMV ------------------------------------------------------------
__global__ __launch_bounds__(256) void q2_split(const float* __restrict__ qn,
    const float* __restrict__ Wq, float* __restrict__ part) {
  __shared__ float ql[64];
  const int cc = blockIdx.x, kc = blockIdx.y, t = threadIdx.x;
  if (t < 64) ql[t] = qn[kc * 64 + t];
  __syncthreads();
  const int c = cc * 256 + t;
  float acc = 0.f;
#pragma unroll 8
  for (int k = 0; k < 64; ++k) acc += ql[k] * Wq[(size_t)(kc * 64 + k) * ND + c];
  part[kc * ND + c] = acc;
}
__global__ __launch_bounds__(256) void q2_red(const float* __restrict__ part,
    const float* __restrict__ bq, float* __restrict__ qh) {
  const int c = blockIdx.x * 256 + threadIdx.x;
  float a = bq[c];
#pragma unroll
  for (int i = 0; i < 16; ++i) a += part[i * ND + c];
  qh[c] = a;
}

// ------------- probe vectors (coalesced LDS-staged) ---------------------------------------
__global__ __launch_bounds__(256) void q3_kernel(const float* __restrict__ Wk,
    const float* __restrict__ bk, const float* __restrict__ qh,
    float* __restrict__ wTf, float* __restrict__ sb) {
  __shared__ float ql[ND];
  __shared__ float wl[4 * ND];
  const int t = threadIdx.x;
  *(f32x4*)&ql[t * 4] = *(const f32x4*)&qh[t * 4];
  const int d0 = blockIdx.x * 4;
  const float* src = Wk + (size_t)d0 * ND;
#pragma unroll
  for (int i = 0; i < 4; ++i)
    *(f32x4*)&wl[(i * 256 + t) * 4] = *(const f32x4*)&src[(size_t)(i * 256 + t) * 4];
  __syncthreads();
  if (t < 64) {
    const int dl = t >> 4, h = t & 15;
    const float* wr_ = wl + dl * ND + h * 64;
    const float* qr = ql + h * 64;
    float acc = 0.f;
#pragma unroll 8
    for (int j = 0; j < 64; ++j) acc += wr_[j] * qr[j];
    wTf[h * ND + d0 + dl] = acc * 0.125f;
  } else if (blockIdx.x == 0 && t >= 64 && t < 80) {
    const int h = t - 64;
    float sv = 0.f;
    for (int j = 0; j < 64; ++j) sv += bk[h * 64 + j] * ql[h * 64 + j];
    sb[h] = sv * 0.125f;
  }
}

// ------------- fold LN into probes; gwP = MFMA-B-fragment-packed bf16 gw -------------------
__global__ __launch_bounds__(256) void q4_kernel(const float* __restrict__ wTf,
    const float* __restrict__ g_kv, const float* __restrict__ be_kv,
    const float* __restrict__ sb, u16* __restrict__ gwP, float* __restrict__ cgw,
    float* __restrict__ cbw) {
  __shared__ float red[8];
  const int h = blockIdx.x, t = threadIdx.x;
  float pg = 0.f, pb = 0.f;
  for (int d = t; d < ND; d += 256) {
    const float w = wTf[h * ND + d];
    const float gw = g_kv[d] * w;
    gwP[(d >> 5) * 512 + (h + 16 * ((d >> 3) & 3)) * 8 + (d & 7)] = f2b(gw);
    pg += gw;
    pb += be_kv[d] * w;
  }
  bsum2(pg, pb, red, t);
  if (t == 0) { cgw[h] = pg; cbw[h] = pb + sb[h]; }
}

// ------------- scores: MFMA tall-skinny, 16 rows/wave x 16 heads, K=1024 ------------------
__global__ __launch_bounds__(256) void scores3(const float* __restrict__ reasoning,
    const float* __restrict__ se_d, const u16* __restrict__ gwP,
    const float* __restrict__ cgw, const float* __restrict__ cbw,
    float* __restrict__ scores, float* __restrict__ stats) {
  __shared__ u16 gwl[16384];     // 32 KB: B-fragments for all 32 k-tiles
  __shared__ float smv[4][16], srv[4][16];
  const int t = threadIdx.x, wv = t >> 6, lane = t & 63;
#pragma unroll
  for (int i = 0; i < 8; ++i)
    gld16(gwP + (i * 256 + t) * 8, gwl + i * 2048 + wv * 512);
  const int r0 = blockIdx.x * 64 + wv * 16;
  const int rowA = r0 + (lane & 15);
  const unsigned bA = (unsigned)rowA / NKV;
  const int kA = rowA - bA * NKV;
  const float* ptr = ((kA < NS) ? reasoning + ((size_t)bA * NS + kA) * ND
                                : se_d + (size_t)bA * ND) + (lane >> 4) * 8;
  __syncthreads();
  f32x4 acc;
#pragma unroll
  for (int j = 0; j < 4; ++j) acc[j] = 0.f;
  float s = 0.f, q = 0.f;
  for (int kt = 0; kt < 32; ++kt) {
    const f32x4 v0 = *(const f32x4*)(ptr + kt * 32);
    const f32x4 v1 = *(const f32x4*)(ptr + kt * 32 + 4);
    bf16x8 af;
#pragma unroll
    for (int j = 0; j < 4; ++j) {
      af[j] = (short)f2b(v0[j]);
      af[4 + j] = (short)f2b(v1[j]);
      s += v0[j] + v1[j];
      q += v0[j] * v0[j] + v1[j] * v1[j];
    }
    const bf16x8 bfr = *(const bf16x8*)(gwl + kt * 512 + lane * 8);
    acc = __builtin_amdgcn_mfma_f32_16x16x32_bf16(af, bfr, acc, 0, 0, 0);
  }
  s += __shfl_xor(s, 16, 64); s += __shfl_xor(s, 32, 64);
  q += __shfl_xor(q, 16, 64); q += __shfl_xor(q, 32, 64);
  const float m = s * (1.f / ND);
  const float rstd = rsqrtf(q * (1.f / ND) - m * m + 1e-5f);
  if (lane < 16) {
    smv[wv][lane] = m; srv[wv][lane] = rstd;
    const int row = r0 + lane;
    stats[(size_t)row * 2] = m;
    stats[(size_t)row * 2 + 1] = rstd;
  }
  __syncthreads();
  const int h = lane & 15;
  const float cg = cgw[h], cb = cbw[h];
#pragma unroll
  for (int j = 0; j < 4; ++j) {
    const int lr = (lane >> 4) * 4 + j;
    const int row = r0 + lr;
    const float mm = smv[wv][lr], rr = srv[wv][lr];
    const unsigned b = (unsigned)row / NKV;
    const int k = row - b * NKV;
    scores[((size_t)b * NH + h) * NKV + k] = rr * acc[j] - rr * mm * cg + cb;
  }
}

// ------------- softmax + streaming weighted sum -> ctxb bf16 ------------------------------
__global__ __launch_bounds__(256) void ctx2(const float* __restrict__ reasoning,
    const float* __restrict__ se_d, const float* __restrict__ scores,
    const float* __restrict__ stats, const float* __restrict__ g_kv,
    const float* __restrict__ be_kv, u16* __restrict__ ctxb) {
  __shared__ float sc[NH][260];
  __shared__ float stm[NKV], str[NKV];
  __shared__ float c1s[NH];
  const int chunk = blockIdx.x, b = blockIdx.y;
  const int t = threadIdx.x, wv = t >> 6, lane = t & 63;
#pragma unroll
  for (int h = 0; h < NH; ++h)
    for (int k = t; k < NKV; k += 256) sc[h][k] = scores[((size_t)b * NH + h) * NKV + k];
  for (int k = t; k < NKV; k += 256) {
    stm[k] = stats[((size_t)b * NKV + k) * 2];
    str[k] = stats[((size_t)b * NKV + k) * 2 + 1];
  }
  __syncthreads();
#pragma unroll
  for (int hh = 0; hh < 4; ++hh) {
    const int h = wv * 4 + hh;
    float mx = -1e30f;
    for (int i = 0; i < 5; ++i) { const int k = lane + i * 64; if (k < NKV) mx = fmaxf(mx, sc[h][k]); }
#pragma unroll
    for (int o = 32; o > 0; o >>= 1) mx = fmaxf(mx, __shfl_xor(mx, o, 64));
    float sm = 0.f;
    for (int i = 0; i < 5; ++i) {
      const int k = lane + i * 64;
      if (k < NKV) { const float e = __expf(sc[h][k] - mx); sc[h][k] = e; sm += e; }
    }
#pragma unroll
    for (int o = 32; o > 0; o >>= 1) sm += __shfl_xor(sm, o, 64);
    const float inv = 1.f / sm;
    float c1 = 0.f;
    for (int i = 0; i < 5; ++i) {
      const int k = lane + i * 64;
      if (k < NKV) {
        const float a = sc[h][k] * inv * str[k];
        sc[h][k] = a;
        c1 += a * stm[k];
      }
    }
#pragma unroll
    for (int o = 32; o > 0; o >>= 1) c1 += __shfl_xor(c1, o, 64);
    if (lane == 0) c1s[h] = c1;
  }
  __syncthreads();
  const int c = chunk * 256 + t;
  const float g = g_kv[c], be = be_kv[c];
  float acc[16];
#pragma unroll
  for (int h = 0; h < 16; ++h) acc[h] = 0.f;
  const float* xc = reasoning + (size_t)b * NS * ND + c;
#pragma unroll 2
  for (int k4 = 0; k4 < 64; ++k4) {
    const float x0 = xc[(size_t)(k4 * 4 + 0) * ND];
    const float x1 = xc[(size_t)(k4 * 4 + 1) * ND];
    const float x2 = xc[(size_t)(k4 * 4 + 2) * ND];
    const float x3 = xc[(size_t)(k4 * 4 + 3) * ND];
#pragma unroll
    for (int h = 0; h < 16; ++h) {
      const f32x4 w = *(const f32x4*)&sc[h][k4 * 4];
      acc[h] += w[0] * x0 + w[1] * x1 + w[2] * x2 + w[3] * x3;
    }
  }
  {
    const float xs = se_d[(size_t)b * ND + c];
#pragma unroll
    for (int h = 0; h < 16; ++h) acc[h] += sc[h][NS] * xs;
  }
#pragma unroll
  for (int h = 0; h < 16; ++h)
    ctxb[((size_t)b * NH + h) * ND + c] = f2b(g * (acc[h] - c1s[h]) + be);
}

extern "C" void kernel_launch(void* const* d_in, const int* in_sizes, int n_in,
                              void* d_out, int out_size, void* d_ws, size_t ws_size,
                              hipStream_t stream) {
  (void)in_sizes; (void)n_in; (void)out_size; (void)ws_size;
  const float* reasoning = (const float*)d_in[0];
  const float* state  = (const float*)d_in[1];
  const float* x0     = (const float*)d_in[2];
  const float* W_se   = (const float*)d_in[3];
  const float* b_se   = (const float*)d_in[4];
  const float* g_se   = (const float*)d_in[5];
  const float* be_se  = (const float*)d_in[6];
  const float* W_ap   = (const float*)d_in[7];
  const float* b_ap   = (const float*)d_in[8];
  const float* W_ad   = (const float*)d_in[9];
  const float* b_ad   = (const float*)d_in[10];
  const float* mem_latent = (const float*)d_in[11];
  const float* Wq = (const float*)d_in[12]; const float* bq = (const float*)d_in[13];
  const float* Wk = (const float*)d_in[14]; const float* bk = (const float*)d_in[15];
  const float* Wv = (const float*)d_in[16]; const float* bv = (const float*)d_in[17];
  const float* Wo = (const float*)d_in[18]; const float* bo = (const float*)d_in[19];
  const float* g_q  = (const float*)d_in[20]; const float* be_q  = (const float*)d_in[21];
  const float* g_kv = (const float*)d_in[22]; const float* be_kv = (const float*)d_in[23];
  const float* W_fp = (const float*)d_in[24]; const float* b_fp = (const float*)d_in[25];
  const float* pos_emb = (const float*)d_in[26];
  const float* filmW  = (const float*)d_in[27]; const float* filmb  = (const float*)d_in[28];
  const float* filmg  = (const float*)d_in[29]; const float* filmbe = (const float*)d_in[30];
  const float* filmWf = (const float*)d_in[31]; const float* filmbf = (const float*)d_in[32];

  char* base = (char*)d_ws;
  size_t off = 0;
  auto alloc = [&](size_t bytes) -> void* {
    void* p = base + off;
    off += (bytes + 255) & ~(size_t)255;
    return p;
  };
  u16*  Wpack   = (u16*)alloc((size_t)NL * ND * ND * 2);        // filmW^T
  u16*  Wfp2    = (u16*)alloc((size_t)NL * 2 * ND * ND * 2);    // filmWf^T
  u16*  Wvp     = (u16*)alloc((size_t)ND * ND * 2);
  u16*  Wop     = (u16*)alloc((size_t)ND * ND * 2);
  u16*  Wfpp    = (u16*)alloc((size_t)ND * ND * 2);
  u16*  WapP    = (u16*)alloc((size_t)NA * ND * 2);
  u16*  WadP    = (u16*)alloc((size_t)32768 * 2);
  float* bt     = (float*)alloc((size_t)NSTEPS * ND * 4);
  float* se_d   = (float*)alloc((size_t)NB * ND * 4);
  float* qn     = (float*)alloc((size_t)ND * 4);
  float* qh     = (float*)alloc((size_t)ND * 4);
  float* part   = (float*)alloc((size_t)16 * ND * 4);
  float* wTf    = (float*)alloc((size_t)NH * ND * 4);
  float* sb     = (float*)alloc((size_t)NH * 4);
  u16*  gwP     = (u16*)alloc((size_t)NH * ND * 2);
  float* cgw    = (float*)alloc((size_t)NH * 4);
  float* cbw    = (float*)alloc((size_t)NH * 4);
  float* stats  = (float*)alloc((size_t)NB * NKV * 2 * 4);
  float* scores = (float*)alloc((size_t)NB * NH * NKV * 4);
  u16*  ctxb    = (u16*)alloc((size_t)NB * NH * ND * 2);
  u16*  mem_pre = (u16*)alloc((size_t)NB * ND * 2);
  u16*  memb    = (u16*)alloc((size_t)NB * ND * 2);
  u16*  fvb     = (u16*)alloc((size_t)NB * ND * 2);
  u16*  gbB     = (u16*)alloc((size_t)NL * NB * 2 * ND * 2);
  u16*  hbuf    = (u16*)alloc((size_t)NM * ND * 2);
  u16*  ubuf    = (u16*)alloc((size_t)NM * ND * 2);

  // ---- weight packs ----
  packT<<<dim3(16, 16, NL), 256, 0, stream>>>(filmW, (long long)ND * ND, ND, Wpack,
                                              (long long)ND * ND);
  packT<<<dim3(32, 16, NL), 256, 0, stream>>>(filmWf, (long long)ND * 2 * ND, 2 * ND, Wfp2,
                                              (long long)2 * ND * ND);
  packT<<<dim3(16, 16, 1), 256, 0, stream>>>(Wv, 0, ND, Wvp, 0);
  packT<<<dim3(16, 16, 1), 256, 0, stream>>>(Wo, 0, ND, Wop, 0);
  packT<<<dim3(16, 16, 1), 256, 0, stream>>>(W_fp, 0, ND, Wfpp, 0);
  prep_misc<<<32, 256, 0, stream>>>(W_ap, W_ad, WapP, WadP, b_ap, bt);

  // ---- attention / conditioning chain ----
  se_kernel<<<NB, 256, 0, stream>>>(state, W_se, b_se, g_se, be_se, se_d);
  q1_kernel<<<1, 256, 0, stream>>>(mem_latent, g_q, be_q, qn);
  q2_split<<<dim3(4, 16), 256, 0, stream>>>(qn, Wq, part);
  q2_red<<<4, 256, 0, stream>>>(part, bq, qh);
  q3_kernel<<<256, 256, 0, stream>>>(Wk, bk, qh, wTf, sb);
  q4_kernel<<<NH, 256, 0, stream>>>(wTf, g_kv, be_kv, sb, gwP, cgw, cbw);
  scores3<<<(NB * NKV) / 64, 256, 0, stream>>>(reasoning, se_d, gwP, cgw, cbw, scores, stats);
  ctx2<<<dim3(4, NB), 256, 0, stream>>>(reasoning, se_d, scores, stats, g_kv, be_kv, ctxb);
  bgemm<<<dim3(1, 16), 256, 0, stream>>>(ctxb, NH * ND, ND, Wvp, (long long)64 * ND, bv, 64,
                                         mem_pre, ND, 64);
  bgemm<<<dim3(16, 1), 256, 0, stream>>>(mem_pre, ND, 0, Wop, 0, bo, 0, memb, ND, 0);
  bgemm<<<dim3(16, 1), 256, 0, stream>>>(memb, ND, 0, Wfpp, 0, b_fp, 0, fvb, ND, 0);
  bgemm<<<dim3(32, NL), 256, 0, stream>>>(fvb, ND, 0, Wfp2, (long long)2 * ND * ND, filmbf,
                                          2 * ND, gbB, 2 * ND, (long long)NB * 2 * ND);

  // ---- flow-matching Euler loop ----
  for (int s = 0; s < NSTEPS; ++s) {
    const float* xin = (s == 0) ? x0 : (const float*)d_out;
    h0_mfma<<<dim3(NM / 128, 8), 256, 0, stream>>>(xin, WapP, bt + (size_t)s * ND, pos_emb,
                                                   hbuf);
    for (int l = 0; l < NL; ++l) {
      film_gemm<<<400, 512, 0, stream>>>(hbuf, Wpack + (size_t)l * ND * ND, ubuf);
      ln_film<<<NM / 4, 256, 0, stream>>>(ubuf, filmb + (size_t)l * ND, filmg + (size_t)l * ND,
                                          filmbe + (size_t)l * ND,
                                          gbB + (size_t)l * NB * 2 * ND, hbuf);
    }
    vx_kernel<<<NM / 64, 256, 0, stream>>>(hbuf, WadP, b_ad, xin, (float*)d_out);
  }
}